// Round 1
// baseline (942.434 us; speedup 1.0000x reference)
//
#include <hip/hip_runtime.h>

#define BB 64
#define CC 3
#define HH 224
#define WW 224
#define KK 37
#define PP 18          // KK/2
#define TILE 32
#define IN_T 68        // TILE + KK - 1
#define IN_STRIDE 72   // padded row stride (16B-aligned, 2-way bank alias only)
#define K_STRIDE 40    // kernel row stride (16B-aligned)

__global__ __launch_bounds__(256) void optics_conv(
    const float* __restrict__ batch,
    const float* __restrict__ psf,
    const int* __restrict__ params,
    const float* __restrict__ weights,
    float* __restrict__ out)
{
    __shared__ __align__(16) float s_in[IN_T * IN_STRIDE]; // 68*72*4B = 19.1 KB
    __shared__ __align__(16) float s_k[KK * K_STRIDE];     // 37*40*4B = 5.9 KB

    const int tileX = blockIdx.x;
    const int tileY = blockIdx.y;
    const int plane = blockIdx.z;          // b*3 + c
    const int b = plane / CC;
    const int c = plane - b * CC;
    const int tid = threadIdx.x;

    // --- stage per-plane kernel: psf[params[b], SEVERITY-1=2, 0, c, :, :] ---
    const int p = params[b];
    // psf layout (8,5,1,3,37,37): offset = ((p*5 + 2)*3 + c) * 37*37
    const float* ksrc = psf + (size_t)((p * 5 + 2) * CC + c) * (KK * KK);
    for (int i = tid; i < KK * KK; i += 256) {
        int ky = i / KK, kx = i - ky * KK;
        s_k[ky * K_STRIDE + kx] = ksrc[i];
    }

    // --- stage 68x68 reflect-padded input tile ---
    const float* src = batch + (size_t)plane * (HH * WW);
    const int py0 = tileY * TILE - PP;
    const int px0 = tileX * TILE - PP;
    for (int i = tid; i < IN_T * IN_T; i += 256) {
        int ly = i / IN_T, lx = i - ly * IN_T;
        int iy = py0 + ly;
        iy = iy < 0 ? -iy : (iy >= HH ? 2 * HH - 2 - iy : iy);
        int ix = px0 + lx;
        ix = ix < 0 ? -ix : (ix >= WW ? 2 * WW - 2 - ix : ix);
        s_in[ly * IN_STRIDE + lx] = src[iy * WW + ix];
    }
    __syncthreads();

    // --- compute: each thread owns 4 consecutive x outputs of one row ---
    const int tx = tid & 7;       // 8 threads across x -> 32 cols
    const int ty = tid >> 3;      // 32 rows
    const int x4 = tx * 4;

    float acc0 = 0.f, acc1 = 0.f, acc2 = 0.f, acc3 = 0.f;
    for (int ky = 0; ky < KK; ++ky) {
        const float4* rbase = (const float4*)(&s_in[(ty + ky) * IN_STRIDE + x4]);
        float row[40];
        #pragma unroll
        for (int q = 0; q < 10; ++q) {
            float4 v = rbase[q];
            row[q * 4 + 0] = v.x; row[q * 4 + 1] = v.y;
            row[q * 4 + 2] = v.z; row[q * 4 + 3] = v.w;
        }
        const float4* kbase = (const float4*)(&s_k[ky * K_STRIDE]);
        float kv[40];
        #pragma unroll
        for (int q = 0; q < 10; ++q) {
            float4 v = kbase[q];
            kv[q * 4 + 0] = v.x; kv[q * 4 + 1] = v.y;
            kv[q * 4 + 2] = v.z; kv[q * 4 + 3] = v.w;
        }
        #pragma unroll
        for (int kx = 0; kx < KK; ++kx) {
            acc0 += row[kx + 0] * kv[kx];
            acc1 += row[kx + 1] * kv[kx];
            acc2 += row[kx + 2] * kv[kx];
            acc3 += row[kx + 3] * kv[kx];
        }
    }

    // --- epilogue: blend with original (recovered from LDS tile interior) ---
    const float w = weights[b];
    const int oy = tileY * TILE + ty;
    const int ox = tileX * TILE + x4;
    float* dst = out + (size_t)plane * (HH * WW) + oy * WW + ox;
    const float* ctr = &s_in[(ty + PP) * IN_STRIDE + x4 + PP];
    dst[0] = (1.f - w) * ctr[0] + w * acc0;
    dst[1] = (1.f - w) * ctr[1] + w * acc1;
    dst[2] = (1.f - w) * ctr[2] + w * acc2;
    dst[3] = (1.f - w) * ctr[3] + w * acc3;
}

__global__ void copy_targets(const int* __restrict__ t, float* __restrict__ out) {
    int i = threadIdx.x;
    if (i < BB) out[i] = (float)t[i];
}

extern "C" void kernel_launch(void* const* d_in, const int* in_sizes, int n_in,
                              void* d_out, int out_size, void* d_ws, size_t ws_size,
                              hipStream_t stream) {
    const float* batch   = (const float*)d_in[0];
    const int*   targets = (const int*)d_in[1];
    const float* psf     = (const float*)d_in[2];
    const int*   params  = (const int*)d_in[3];
    const float* weights = (const float*)d_in[4];
    float* out = (float*)d_out;

    dim3 grid(WW / TILE, HH / TILE, BB * CC);   // 7 x 7 x 192
    optics_conv<<<grid, 256, 0, stream>>>(batch, psf, params, weights, out);

    copy_targets<<<1, 64, 0, stream>>>(targets, out + (size_t)BB * CC * HH * WW);
}

// Round 2
// 136.924 us; speedup vs baseline: 6.8829x; 6.8829x over previous
//
#include <hip/hip_runtime.h>

#define BB 64
#define CC 3
#define HH 224
#define WW 224
#define KK 37
#define PP 18
#define PLANE (HH*WW)
#define NPARAM 8

// input band: 68 rows x 280 bf16, stride 280 (560B; 560/16=35 == 3 mod 8 -> bank-spread)
#define BROWS 68
#define BSTR  280
// Toeplitz slab: 32 x 88 bf16, stride 88 (176B; 11 == 3 mod 8 -> bank-spread)
#define TROWS 32
#define TSTR  88
#define TELEMS (TROWS*TSTR)      // 2816
#define NTT (NPARAM*CC*KK)       // 888 distinct (param, channel, ky) slabs

typedef __attribute__((ext_vector_type(8)))  __bf16 bf16x8;
typedef __attribute__((ext_vector_type(16))) float  f32x16;

__device__ __forceinline__ unsigned short f2bf(float f) {
    unsigned int u = __float_as_uint(f);
    return (unsigned short)((u + 0x7FFFu + ((u >> 16) & 1u)) >> 16);   // RNE
}
__device__ __forceinline__ float bf2f(unsigned short h) {
    return __uint_as_float(((unsigned int)h) << 16);
}

// Prebuild all 888 Toeplitz slabs: tt[(p*3+c)*37+ky][mx*88+cq] = w[ky][cq-mx] (bf16, 0 outside band)
__global__ __launch_bounds__(256) void build_toeplitz(
    const float* __restrict__ psf, unsigned short* __restrict__ tt)
{
    const int blk = blockIdx.x;              // (p*3+c)*37 + ky
    const int ky = blk % KK;
    const int pc = blk / KK;
    const int p = pc / CC, c = pc - (pc / CC) * CC;
    const float* wrow = psf + (size_t)(((p*5 + 2)*CC + c)*KK + ky) * KK;
    unsigned short* dst = tt + (size_t)blk * TELEMS;
    for (int e = threadIdx.x; e < TELEMS; e += 256) {
        int mx = e / TSTR, cq = e - mx*TSTR;
        int kx = cq - mx;
        unsigned short v = 0;
        if (kx >= 0 && kx < KK) v = f2bf(wrow[kx]);
        dst[e] = v;
    }
}

template<bool FROM_WS>
__global__ __launch_bounds__(256) void optics_mfma(
    const float* __restrict__ batch,
    const float* __restrict__ psf,
    const unsigned short* __restrict__ tt,
    const int* __restrict__ params,
    const float* __restrict__ weights,
    float* __restrict__ out)
{
    __shared__ __align__(16) unsigned short s_band[BROWS*BSTR];   // 38080 B
    __shared__ __align__(16) unsigned short s_tt[2][TELEMS];      // 11264 B
    __shared__ __align__(16) float s_w[FROM_WS ? 4 : KK*40];      // fallback only

    const int tid = threadIdx.x;
    const int yband = blockIdx.x;            // 0..6
    const int plane = blockIdx.y;            // 0..191
    const int b = plane / CC, c = plane - b*CC;
    const int y0 = yband * 32;
    const int p = params[b];

    // --- stage reflect-padded input band, fp32 -> bf16 ---
    const float* src = batch + (size_t)plane * PLANE;
    for (int i = tid; i < BROWS*BSTR; i += 256) {
        int r = i / BSTR, cc_ = i - r*BSTR;
        int gy = y0 + r - PP;
        gy = gy < 0 ? -gy : (gy >= HH ? 2*HH - 2 - gy : gy);
        int gx = cc_ - PP;
        gx = gx < 0 ? -gx : (gx >= WW ? 2*WW - 2 - gx : gx);
        s_band[r*BSTR + cc_] = f2bf(src[gy*WW + gx]);
    }

    const unsigned short* ttp = tt + (size_t)((p*CC + c)*KK) * TELEMS;

    if constexpr (FROM_WS) {
        const uint4* s = (const uint4*)ttp;               // ky = 0 slab
        uint4* d = (uint4*)s_tt[0];
        d[tid] = s[tid];
        if (tid < TELEMS/8 - 256) d[256 + tid] = s[256 + tid];
        __syncthreads();
    } else {
        const float* ksrc = psf + (size_t)((p*5 + 2)*CC + c) * (KK*KK);
        for (int i = tid; i < KK*KK; i += 256) {
            int ky_ = i / KK, kx_ = i - ky_*KK;
            s_w[ky_*40 + kx_] = ksrc[i];
        }
        __syncthreads();
        for (int e = tid; e < TELEMS; e += 256) {
            int mx = e / TSTR, cq = e - mx*TSTR;
            int kx = cq - mx;
            unsigned short v = 0;
            if (kx >= 0 && kx < KK) v = f2bf(s_w[kx]);    // ky = 0
            s_tt[0][e] = v;
        }
        __syncthreads();
    }

    const int lane = tid & 63;
    const int wid  = tid >> 6;               // 0..3
    const int ln   = lane & 31;
    const int hi   = lane >> 5;
    const int t0   = 2*wid;                  // first x-tile of this wave
    const int nt   = (wid == 3) ? 1 : 2;     // wave 3 owns only tile 6
    const int g0   = 4*wid;                  // first 16-col chunk
    const int ng   = (wid == 3) ? 5 : 7;

    f32x16 acc0 = {0,0,0,0, 0,0,0,0, 0,0,0,0, 0,0,0,0};
    f32x16 acc1 = {0,0,0,0, 0,0,0,0, 0,0,0,0, 0,0,0,0};

    for (int ky = 0; ky < KK; ++ky) {
        const int cur = ky & 1;
        // stage/build next ky's Toeplitz slab into the other buffer
        if (ky + 1 < KK) {
            if constexpr (FROM_WS) {
                const uint4* s = (const uint4*)(ttp + (size_t)(ky + 1)*TELEMS);
                uint4* d = (uint4*)s_tt[cur ^ 1];
                d[tid] = s[tid];
                if (tid < TELEMS/8 - 256) d[256 + tid] = s[256 + tid];
            } else {
                for (int e = tid; e < TELEMS; e += 256) {
                    int mx = e / TSTR, cq = e - mx*TSTR;
                    int kx = cq - mx;
                    unsigned short v = 0;
                    if (kx >= 0 && kx < KK) v = f2bf(s_w[(ky + 1)*40 + kx]);
                    s_tt[cur ^ 1][e] = v;
                }
            }
        }

        // --- compute ky ---
        const unsigned short* tb = s_tt[cur];
        bf16x8 bq[5];
        #pragma unroll
        for (int q = 0; q < 5; ++q)
            bq[q] = *(const bf16x8*)&tb[ln*TSTR + 16*q + 8*hi];
        bf16x8 af[7];
        #pragma unroll
        for (int gi = 0; gi < 7; ++gi)
            if (gi < ng)
                af[gi] = *(const bf16x8*)&s_band[(ky + ln)*BSTR + 16*(g0 + gi) + 8*hi];
        #pragma unroll
        for (int q = 0; q < 5; ++q)
            acc0 = __builtin_amdgcn_mfma_f32_32x32x16_bf16(af[q], bq[q], acc0, 0, 0, 0);
        if (nt == 2) {
            #pragma unroll
            for (int q = 0; q < 5; ++q)
                acc1 = __builtin_amdgcn_mfma_f32_32x32x16_bf16(af[q + 2], bq[q], acc1, 0, 0, 0);
        }
        __syncthreads();
    }

    // --- epilogue: blend and store (coalesced 128B per reg per half-wave) ---
    const float wt = weights[b];
    const float w1 = 1.0f - wt;
    float* dst = out + (size_t)plane * PLANE;
    #pragma unroll
    for (int r = 0; r < 16; ++r) {
        const int row = (r & 3) + 8*(r >> 2) + 4*hi;     // 0..31 (m74 D layout)
        const int yo = y0 + row;
        {
            const int xo = 32*t0 + ln;
            const float orig = bf2f(s_band[(row + PP)*BSTR + xo + PP]);
            dst[yo*WW + xo] = w1*orig + wt*acc0[r];
        }
        if (nt == 2) {
            const int xo = 32*(t0 + 1) + ln;
            const float orig = bf2f(s_band[(row + PP)*BSTR + xo + PP]);
            dst[yo*WW + xo] = w1*orig + wt*acc1[r];
        }
    }
}

__global__ void copy_targets(const int* __restrict__ t, float* __restrict__ out) {
    int i = threadIdx.x;
    if (i < BB) out[i] = (float)t[i];
}

extern "C" void kernel_launch(void* const* d_in, const int* in_sizes, int n_in,
                              void* d_out, int out_size, void* d_ws, size_t ws_size,
                              hipStream_t stream) {
    const float* batch   = (const float*)d_in[0];
    const int*   targets = (const int*)d_in[1];
    const float* psf     = (const float*)d_in[2];
    const int*   params  = (const int*)d_in[3];
    const float* weights = (const float*)d_in[4];
    float* out = (float*)d_out;
    unsigned short* tt = (unsigned short*)d_ws;

    const size_t need = (size_t)NTT * TELEMS * sizeof(unsigned short);  // ~5.0 MB
    dim3 grid(HH/32, BB*CC);                  // 7 x 192

    if (ws_size >= need) {
        build_toeplitz<<<NTT, 256, 0, stream>>>(psf, tt);
        optics_mfma<true><<<grid, 256, 0, stream>>>(batch, psf, tt, params, weights, out);
    } else {
        optics_mfma<false><<<grid, 256, 0, stream>>>(batch, psf, tt, params, weights, out);
    }
    copy_targets<<<1, 64, 0, stream>>>(targets, out + (size_t)BB*CC*PLANE);
}

// Round 4
// 92.557 us; speedup vs baseline: 10.1821x; 1.4793x over previous
//
#include <hip/hip_runtime.h>

#define BB 64
#define CC 3
#define HH 224
#define WW 224
#define KK 37
#define PP 18
#define PLANE (HH*WW)

#define BM 64            // output rows per block
#define BROWS 100        // BM + KK - 1
#define BSTR  280        // band row stride in shorts (0-conflict pattern, measured)
#define TSTR  88         // Toeplitz row stride in shorts
#define TELEMS (32*TSTR) // 2816
#define SLABP 3072       // padded slab stride in shorts (6144 B = 384 x 16B)
#define NTT (8*CC*KK)    // 888 slabs

typedef __attribute__((ext_vector_type(8)))  __bf16 bf16x8;
typedef __attribute__((ext_vector_type(16))) float  f32x16;

__device__ __forceinline__ unsigned short f2bf(float f) {
    unsigned int u = __float_as_uint(f);
    return (unsigned short)((u + 0x7FFFu + ((u >> 16) & 1u)) >> 16);   // RNE
}
__device__ __forceinline__ float bf2f(unsigned short h) {
    return __uint_as_float(((unsigned int)h) << 16);
}

__global__ __launch_bounds__(256) void build_toeplitz(
    const float* __restrict__ psf, unsigned short* __restrict__ tt)
{
    const int blk = blockIdx.x;              // (p*3+c)*37 + ky
    const int ky = blk % KK;
    const int pc = blk / KK;
    const int p = pc / CC, c = pc - (pc / CC) * CC;
    const float* wrow = psf + (size_t)(((p*5 + 2)*CC + c)*KK + ky) * KK;
    unsigned short* dst = tt + (size_t)blk * SLABP;
    for (int e = threadIdx.x; e < TELEMS; e += 256) {
        int mx = e / TSTR, cq = e - mx*TSTR;
        int kx = cq - mx;
        unsigned short v = 0;
        if (kx >= 0 && kx < KK) v = f2bf(wrow[kx]);
        dst[e] = v;
    }
}

template<bool FROM_WS>
__global__ __launch_bounds__(512, 4) void optics_mfma(
    const float* __restrict__ batch,
    const float* __restrict__ psf,
    const unsigned short* __restrict__ tt,
    const int* __restrict__ params,
    const float* __restrict__ weights,
    float* __restrict__ out)
{
    __shared__ __align__(16) unsigned short s_band[BROWS*BSTR];   // 56,000 B
    __shared__ __align__(16) unsigned short s_tt[2][SLABP];       // 12,288 B
    __shared__ __align__(16) float s_w[FROM_WS ? 4 : KK*40];      // fallback only

    const int tid = threadIdx.x;
    const int yband = blockIdx.x;            // 0..3
    const int plane = blockIdx.y;            // 0..191
    const int b = plane / CC, c = plane - b*CC;
    const int y0 = yband * BM;
    const int rows = (HH - y0 < BM) ? (HH - y0) : BM;   // 64 (or 32 for last)
    const int brows = rows + KK - 1;
    const int p = params[b];

    // --- stage reflect-padded band, fp32 -> bf16 ---
    const float* src = batch + (size_t)plane * PLANE;
    // interior: fully-valid gx 0..223 as 56 aligned float4 groups -> cols 18..241
    for (int i = tid; i < brows*56; i += 512) {
        int r = i / 56, g = i - r*56;
        int gy = y0 + r - PP;
        gy = gy < 0 ? -gy : (gy >= HH ? 2*HH - 2 - gy : gy);
        float4 v = *(const float4*)&src[gy*WW + 4*g];
        unsigned int lo  = f2bf(v.x) | ((unsigned int)f2bf(v.y) << 16);
        unsigned int hi2 = f2bf(v.z) | ((unsigned int)f2bf(v.w) << 16);
        unsigned int* d = (unsigned int*)&s_band[r*BSTR + PP + 4*g];
        d[0] = lo; d[1] = hi2;
    }
    // edges: cols 0..17 (left reflect) and 242..279 (right reflect), 56 per row
    for (int i = tid; i < brows*56; i += 512) {
        int r = i / 56, e = i - r*56;
        int col = e < PP ? e : (224 + e);    // e=18..55 -> col 242..279
        int gy = y0 + r - PP;
        gy = gy < 0 ? -gy : (gy >= HH ? 2*HH - 2 - gy : gy);
        int gx = col - PP;
        gx = gx < 0 ? -gx : (gx >= WW ? 2*WW - 2 - gx : gx);
        s_band[r*BSTR + col] = f2bf(src[gy*WW + gx]);
    }

    const unsigned short* ttp = tt + (size_t)((p*CC + c)*KK) * SLABP;

    // --- stage slab for ky = 0 ---
    if constexpr (FROM_WS) {
        if (tid < 384)
            *(uint4*)&s_tt[0][tid*8] = *(const uint4*)(ttp + tid*8);
    } else {
        const float* ksrc = psf + (size_t)((p*5 + 2)*CC + c) * (KK*KK);
        for (int i = tid; i < KK*KK; i += 512) {
            int ky_ = i / KK, kx_ = i - ky_*KK;
            s_w[ky_*40 + kx_] = ksrc[i];
        }
        __syncthreads();
        for (int e = tid; e < TELEMS; e += 512) {
            int mx = e / TSTR, cq = e - mx*TSTR;
            int kx = cq - mx;
            s_tt[0][e] = (kx >= 0 && kx < KK) ? f2bf(s_w[kx]) : (unsigned short)0;
        }
    }
    __syncthreads();

    const int lane = tid & 63;
    const int wid  = tid >> 6;               // 0..7
    const int wr   = wid >> 2;               // row-tile 0/1
    const int wc   = wid & 3;                // x-group 0..3
    const int ln   = lane & 31;
    const int hi   = lane >> 5;
    const int ng   = (wc == 3) ? 5 : 7;
    const int nt   = (wc == 3) ? 1 : 2;      // tiles 2wc(,2wc+1); wc3 -> tile 6
    const bool active = (wr == 0) || (rows > 32);

    f32x16 acc0 = {0,0,0,0, 0,0,0,0, 0,0,0,0, 0,0,0,0};
    f32x16 acc1 = {0,0,0,0, 0,0,0,0, 0,0,0,0, 0,0,0,0};

    int cur = 0;
    for (int ky = 0; ky < KK; ++ky) {
        // issue-early: load next slab to regs before compute (latency hides)
        uint4 sv;
        const bool stg = FROM_WS && (ky + 1 < KK) && (tid < 384);
        if (stg) sv = *(const uint4*)(ttp + (size_t)(ky + 1)*SLABP + tid*8);

        if (active) {
            const unsigned short* tb = s_tt[cur];
            bf16x8 bq[5];
            #pragma unroll
            for (int q = 0; q < 5; ++q)
                bq[q] = *(const bf16x8*)&tb[ln*TSTR + 16*q + 8*hi];
            bf16x8 af[7];
            #pragma unroll
            for (int gi = 0; gi < 7; ++gi)
                if (gi < ng)
                    af[gi] = *(const bf16x8*)&s_band[(32*wr + ky + ln)*BSTR + 16*(4*wc + gi) + 8*hi];
            __builtin_amdgcn_s_setprio(1);
            #pragma unroll
            for (int q = 0; q < 5; ++q)
                acc0 = __builtin_amdgcn_mfma_f32_32x32x16_bf16(af[q], bq[q], acc0, 0, 0, 0);
            if (nt == 2) {
                #pragma unroll
                for (int q = 0; q < 5; ++q)
                    acc1 = __builtin_amdgcn_mfma_f32_32x32x16_bf16(af[q + 2], bq[q], acc1, 0, 0, 0);
            }
            __builtin_amdgcn_s_setprio(0);
        }

        // write-late into the other buffer; prev readers of it were separated
        // by last iteration's barrier, next readers by this one -> 1 barrier/ky
        if constexpr (FROM_WS) {
            if (stg) *(uint4*)&s_tt[cur ^ 1][tid*8] = sv;
        } else {
            if (ky + 1 < KK) {
                for (int e = tid; e < TELEMS; e += 512) {
                    int mx = e / TSTR, cq = e - mx*TSTR;
                    int kx = cq - mx;
                    s_tt[cur ^ 1][e] = (kx >= 0 && kx < KK) ? f2bf(s_w[(ky + 1)*40 + kx])
                                                            : (unsigned short)0;
                }
            }
        }
        __syncthreads();
        cur ^= 1;
    }

    // --- epilogue: blend + store (coalesced 128B per half-wave row) ---
    if (active) {
        const float wt = weights[b];
        const float w1 = 1.0f - wt;
        float* dst = out + (size_t)plane * PLANE;
        #pragma unroll
        for (int r = 0; r < 16; ++r) {
            const int rowL = (r & 3) + 8*(r >> 2) + 4*hi;    // 0..31 (m74 D layout)
            const int yo = y0 + 32*wr + rowL;
            const int br = 32*wr + rowL + PP;
            {
                const int xo = 32*(2*wc) + ln;
                const float orig = bf2f(s_band[br*BSTR + xo + PP]);
                dst[yo*WW + xo] = w1*orig + wt*acc0[r];
            }
            if (nt == 2) {
                const int xo = 32*(2*wc + 1) + ln;
                const float orig = bf2f(s_band[br*BSTR + xo + PP]);
                dst[yo*WW + xo] = w1*orig + wt*acc1[r];
            }
        }
    }
}

__global__ void copy_targets(const int* __restrict__ t, float* __restrict__ out) {
    int i = threadIdx.x;
    if (i < BB) out[i] = (float)t[i];
}

extern "C" void kernel_launch(void* const* d_in, const int* in_sizes, int n_in,
                              void* d_out, int out_size, void* d_ws, size_t ws_size,
                              hipStream_t stream) {
    const float* batch   = (const float*)d_in[0];
    const int*   targets = (const int*)d_in[1];
    const float* psf     = (const float*)d_in[2];
    const int*   params  = (const int*)d_in[3];
    const float* weights = (const float*)d_in[4];
    float* out = (float*)d_out;
    unsigned short* tt = (unsigned short*)d_ws;

    const size_t need = (size_t)NTT * SLABP * sizeof(unsigned short);  // ~5.5 MB
    dim3 grid((HH + BM - 1) / BM, BB*CC);     // 4 x 192

    if (ws_size >= need) {
        build_toeplitz<<<NTT, 256, 0, stream>>>(psf, tt);
        optics_mfma<true><<<grid, 512, 0, stream>>>(batch, psf, tt, params, weights, out);
    } else {
        optics_mfma<false><<<grid, 512, 0, stream>>>(batch, psf, tt, params, weights, out);
    }
    copy_targets<<<1, 64, 0, stream>>>(targets, out + (size_t)BB*CC*PLANE);
}

// Round 5
// 79.907 us; speedup vs baseline: 11.7941x; 1.1583x over previous
//
#include <hip/hip_runtime.h>

#define BB 64
#define CC 3
#define HH 224
#define WW 224
#define KK 37
#define PP 18
#define PLANE (HH*WW)

#define BM 64            // output rows per block (2 stripes of 32)
#define BROWS 100        // BM + KK - 1
#define BSTR  280        // band row stride in shorts (2-way alias only, free)
#define FRAGS 2560       // shorts per (slab,ky) fragment block: 5q x 2hi x 32ln x 8j
#define NTT (8*CC*KK)    // 888 (param,channel,ky) fragment blocks

typedef __attribute__((ext_vector_type(8)))  __bf16 bf16x8;
typedef __attribute__((ext_vector_type(16))) float  f32x16;

__device__ __forceinline__ unsigned short f2bf(float f) {
    unsigned int u = __float_as_uint(f);
    return (unsigned short)((u + 0x7FFFu + ((u >> 16) & 1u)) >> 16);   // RNE
}
__device__ __forceinline__ float bf2f(unsigned short h) {
    return __uint_as_float(((unsigned int)h) << 16);
}

// Fragment-ordered Toeplitz: frag[s][q][hi][ln][j] = w[ky][16q+8hi+j - ln] (0 outside band)
// One wave's bq[q] load = 2 x 512B contiguous segments -> perfectly coalesced dwordx4.
__global__ __launch_bounds__(256) void build_frags(
    const float* __restrict__ psf, unsigned short* __restrict__ tt)
{
    const int s = blockIdx.x;                // (p*3+c)*37 + ky
    const int ky = s % KK;
    const int pc = s / KK;
    const int p = pc / CC, c = pc - (pc / CC) * CC;
    const float* wrow = psf + (size_t)(((p*5 + 2)*CC + c)*KK + ky) * KK;
    unsigned short* dst = tt + (size_t)s * FRAGS;
    for (int e = threadIdx.x; e < FRAGS; e += 256) {
        int j = e & 7, ln = (e >> 3) & 31, hi = (e >> 8) & 1, q = e >> 9;
        int kx = 16*q + 8*hi + j - ln;
        dst[e] = (kx >= 0 && kx < KK) ? f2bf(wrow[kx]) : (unsigned short)0;
    }
}

__device__ __forceinline__ void load_bq_ws(bf16x8 (&bq)[5], const unsigned short* kybase) {
    #pragma unroll
    for (int q = 0; q < 5; ++q)
        bq[q] = *(const bf16x8*)(kybase + q*512);
}

__device__ __forceinline__ void load_bq_fb(bf16x8 (&bq)[5], const unsigned short* s_w16,
                                           int ky, int hi, int ln) {
    #pragma unroll
    for (int q = 0; q < 5; ++q) {
        union { bf16x8 v; unsigned short s[8]; } u;
        #pragma unroll
        for (int j = 0; j < 8; ++j) {
            int kx = 16*q + 8*hi + j - ln;
            u.s[j] = (kx >= 0 && kx < KK) ? s_w16[ky*40 + kx] : (unsigned short)0;
        }
        bq[q] = u.v;
    }
}

#define MFMA_(T,Q) T = __builtin_amdgcn_mfma_f32_32x32x16_bf16(af, bq[Q], T, 0, 0, 0)

template<int NT>
__device__ __forceinline__ void compute_ky(const unsigned short* rp, const bf16x8 (&bq)[5],
    f32x16& A0, f32x16& A1, f32x16& A2, f32x16& A3)
{
    bf16x8 af;
#define LDC(c) af = *(const bf16x8*)(rp + 16*(c))
    LDC(0);  MFMA_(A0,0);
    LDC(1);  MFMA_(A0,1);
    LDC(2);  MFMA_(A0,2); MFMA_(A1,0);
    LDC(3);  MFMA_(A0,3); MFMA_(A1,1);
    LDC(4);  MFMA_(A0,4); MFMA_(A1,2); MFMA_(A2,0);
    LDC(5);  MFMA_(A1,3); MFMA_(A2,1);
    if constexpr (NT == 4) {
        LDC(6);  MFMA_(A1,4); MFMA_(A2,2); MFMA_(A3,0);
        LDC(7);  MFMA_(A2,3); MFMA_(A3,1);
        LDC(8);  MFMA_(A2,4); MFMA_(A3,2);
        LDC(9);  MFMA_(A3,3);
        LDC(10); MFMA_(A3,4);
    } else {
        LDC(6);  MFMA_(A1,4); MFMA_(A2,2);
        LDC(7);  MFMA_(A2,3);
        LDC(8);  MFMA_(A2,4);
    }
#undef LDC
}

template<bool FROM_WS, int NT>
__device__ __forceinline__ void kloop(
    const unsigned short* base,              // &s_band[(32wr+ln)*BSTR + 128xh + 8hi]
    const unsigned short* fb,                // ws frag base (incl. lane off) or s_w16
    int hi, int ln,
    f32x16& A0, f32x16& A1, f32x16& A2, f32x16& A3)
{
    bf16x8 bqA[5], bqB[5];
    if constexpr (FROM_WS) load_bq_ws(bqA, fb); else load_bq_fb(bqA, fb, 0, hi, ln);
    for (int ky = 0; ky < KK; ky += 2) {
        if (ky + 1 < KK) {
            if constexpr (FROM_WS) load_bq_ws(bqB, fb + (size_t)(ky + 1)*FRAGS);
            else load_bq_fb(bqB, fb, ky + 1, hi, ln);
        }
        __builtin_amdgcn_s_setprio(1);
        compute_ky<NT>(base + ky*BSTR, bqA, A0, A1, A2, A3);
        __builtin_amdgcn_s_setprio(0);
        if (ky + 1 >= KK) break;
        if (ky + 2 < KK) {
            if constexpr (FROM_WS) load_bq_ws(bqA, fb + (size_t)(ky + 2)*FRAGS);
            else load_bq_fb(bqA, fb, ky + 2, hi, ln);
        }
        __builtin_amdgcn_s_setprio(1);
        compute_ky<NT>(base + (ky + 1)*BSTR, bqB, A0, A1, A2, A3);
        __builtin_amdgcn_s_setprio(0);
    }
}

template<bool FROM_WS>
__global__ __launch_bounds__(256, 2) void optics_mfma(
    const float* __restrict__ batch,
    const float* __restrict__ psf,
    const unsigned short* __restrict__ tt,
    const int* __restrict__ params,
    const float* __restrict__ weights,
    float* __restrict__ out)
{
    __shared__ __align__(16) unsigned short s_band[BROWS*BSTR];       // 56,000 B
    __shared__ __align__(16) unsigned short s_w16[FROM_WS ? 8 : KK*40];

    const int tid = threadIdx.x;
    const int yband = blockIdx.x;            // 0..3
    const int plane = blockIdx.y;            // 0..191
    const int b = plane / CC, c = plane - b*CC;
    const int y0 = yband * BM;
    const int rows = (HH - y0 < BM) ? (HH - y0) : BM;   // 64 (32 for last band)
    const int brows = rows + KK - 1;
    const int p = params[b];

    // --- stage reflect-padded band, fp32 -> bf16 ---
    const float* src = batch + (size_t)plane * PLANE;
    // interior: fully-valid gx 0..223 as 56 aligned float4 groups -> cols 18..241
    for (int i = tid; i < brows*56; i += 256) {
        int r = i / 56, g = i - r*56;
        int gy = y0 + r - PP;
        gy = gy < 0 ? -gy : (gy >= HH ? 2*HH - 2 - gy : gy);
        float4 v = *(const float4*)&src[gy*WW + 4*g];
        unsigned int lo  = f2bf(v.x) | ((unsigned int)f2bf(v.y) << 16);
        unsigned int hi2 = f2bf(v.z) | ((unsigned int)f2bf(v.w) << 16);
        unsigned int* d = (unsigned int*)&s_band[r*BSTR + PP + 4*g];
        d[0] = lo; d[1] = hi2;
    }
    // edges: cols 0..17 (left) and 242..279 (right), reflect both axes
    for (int i = tid; i < brows*56; i += 256) {
        int r = i / 56, e = i - r*56;
        int col = e < PP ? e : (224 + e);    // e=18..55 -> col 242..279
        int gy = y0 + r - PP;
        gy = gy < 0 ? -gy : (gy >= HH ? 2*HH - 2 - gy : gy);
        int gx = col - PP;
        gx = gx < 0 ? -gx : (gx >= WW ? 2*WW - 2 - gx : gx);
        s_band[r*BSTR + col] = f2bf(src[gy*WW + gx]);
    }
    if constexpr (!FROM_WS) {
        const float* ksrc = psf + (size_t)((p*5 + 2)*CC + c) * (KK*KK);
        for (int i = tid; i < KK*KK; i += 256) {
            int ky_ = i / KK, kx_ = i - ky_*KK;
            s_w16[ky_*40 + kx_] = f2bf(ksrc[i]);
        }
    }
    __syncthreads();     // the ONLY barrier: band (and fallback kernel) now read-only

    const int lane = tid & 63;
    const int wid  = tid >> 6;               // 0..3
    const int wr   = wid >> 1;               // stripe 0/1
    const int xh   = wid & 1;                // x-half
    const int ln   = lane & 31;
    const int hi   = lane >> 5;
    const bool active = (wr == 0) || (rows > 32);

    if (active) {
        const unsigned short* fb;
        if constexpr (FROM_WS)
            fb = tt + (size_t)((p*CC + c)*KK)*FRAGS + hi*256 + ln*8;
        else
            fb = s_w16;
        const unsigned short* base = &s_band[(32*wr + ln)*BSTR + 128*xh + 8*hi];

        f32x16 A0 = {0,0,0,0, 0,0,0,0, 0,0,0,0, 0,0,0,0};
        f32x16 A1 = A0, A2 = A0, A3 = A0;

        if (xh == 0) kloop<FROM_WS, 4>(base, fb, hi, ln, A0, A1, A2, A3);
        else         kloop<FROM_WS, 3>(base, fb, hi, ln, A0, A1, A2, A3);

        // --- epilogue: blend + store ---
        const float wt = weights[b];
        const float w1 = 1.0f - wt;
        float* dst = out + (size_t)plane * PLANE;
#define EPI(ACC, GT) { \
        _Pragma("unroll") \
        for (int r = 0; r < 16; ++r) { \
            const int rowL = (r & 3) + 8*(r >> 2) + 4*hi; \
            const int yo = y0 + 32*wr + rowL; \
            const int xo = 32*(GT) + ln; \
            const float orig = bf2f(s_band[(32*wr + rowL + PP)*BSTR + xo + PP]); \
            dst[yo*WW + xo] = w1*orig + wt*ACC[r]; \
        } }
        if (xh == 0) { EPI(A0, 0) EPI(A1, 1) EPI(A2, 2) EPI(A3, 3) }
        else         { EPI(A0, 4) EPI(A1, 5) EPI(A2, 6) }
#undef EPI
    }
}

__global__ void copy_targets(const int* __restrict__ t, float* __restrict__ out) {
    int i = threadIdx.x;
    if (i < BB) out[i] = (float)t[i];
}

extern "C" void kernel_launch(void* const* d_in, const int* in_sizes, int n_in,
                              void* d_out, int out_size, void* d_ws, size_t ws_size,
                              hipStream_t stream) {
    const float* batch   = (const float*)d_in[0];
    const int*   targets = (const int*)d_in[1];
    const float* psf     = (const float*)d_in[2];
    const int*   params  = (const int*)d_in[3];
    const float* weights = (const float*)d_in[4];
    float* out = (float*)d_out;
    unsigned short* tt = (unsigned short*)d_ws;

    const size_t need = (size_t)NTT * FRAGS * sizeof(unsigned short);  // ~4.55 MB
    dim3 grid((HH + BM - 1) / BM, BB*CC);     // 4 x 192 = 768 blocks

    if (ws_size >= need) {
        build_frags<<<NTT, 256, 0, stream>>>(psf, tt);
        optics_mfma<true><<<grid, 256, 0, stream>>>(batch, psf, tt, params, weights, out);
    } else {
        optics_mfma<false><<<grid, 256, 0, stream>>>(batch, psf, tt, params, weights, out);
    }
    copy_targets<<<1, 64, 0, stream>>>(targets, out + (size_t)BB*CC*PLANE);
}